// Round 20
// baseline (130.070 us; speedup 1.0000x reference)
//
#include <hip/hip_runtime.h>
#include <math.h>

#define BB 4
#define SS 512
#define PP 128
#define CC 64
#define KK 64
#define NCTX_ 16
#define TT 64
#define NTILES ((BB*SS)/TT)   // 32

typedef __attribute__((ext_vector_type(8))) short bf16x8;
typedef __attribute__((ext_vector_type(4))) float f32x4;
typedef __attribute__((ext_vector_type(16))) float f32x16;

static __device__ __forceinline__ float bf2f(short h) {
    unsigned u = ((unsigned)(unsigned short)h) << 16;
    return __builtin_bit_cast(float, u);
}
static __device__ __forceinline__ short f2bf(float f) {
    unsigned u = __builtin_bit_cast(unsigned, f);
    unsigned r = (u + 0x7fffu + ((u >> 16) & 1u)) >> 16;
    return (short)(unsigned short)r;
}
// clamp a bf16x8 fragment to [-5,5] in the bf16 bit domain (5.0 = 0x40A0).
static __device__ __forceinline__ bf16x8 clampfrag(bf16x8 h) {
    typedef __attribute__((ext_vector_type(4))) unsigned u32x4;
    u32x4 u = __builtin_bit_cast(u32x4, h);
    #pragma unroll
    for (int i = 0; i < 4; ++i) {
        const unsigned w = u[i];
        const unsigned s = w & 0x80008000u;
        unsigned lo = w & 0x7fffu;
        unsigned hi = (w >> 16) & 0x7fffu;
        lo = lo > 0x40a0u ? 0x40a0u : lo;
        hi = hi > 0x40a0u ? 0x40a0u : hi;
        u[i] = s | lo | (hi << 16);
    }
    return __builtin_bit_cast(bf16x8, u);
}

// ---------------------------------------------------------------------------
// Fused pack kernel (one launch):
//  bid <  4096          : W1 -> 16x16-fragment-major bf16 hi (Phase B operand)
//  bid in [4096, 5120)  : H1 -> 32x32-fragment-major bf16 hi/lo (Phase A)
//  bid in [5120, 5184)  : per-class 32x128 {H2 rows 0-3, fc2w row 4, 0...}
//  bid in [5184, 5312)  : x -> 32x32 B-fragment-major bf16 (hi plane only)
// 32x32x16 A/B fragment layout: elem (row=lane&31, k=(lane>>5)*8+e).
// ---------------------------------------------------------------------------
__global__ __launch_bounds__(256) void pack_kernel(
    const float* __restrict__ W1, const float* __restrict__ H1,
    const float* __restrict__ H2, const float* __restrict__ fc2w,
    const float* __restrict__ x,
    short* __restrict__ W1h, short* __restrict__ H1h32, short* __restrict__ H1l32,
    short* __restrict__ H2Wh, short* __restrict__ H2Wl,
    short* __restrict__ xpk)
{
    const int bid  = blockIdx.x;
    const int w    = threadIdx.x >> 6;
    const int lane = threadIdx.x & 63;

    if (bid < CC * KK) {
        // ---- W1 pack: 16x16 fragments, hi plane only ----
        const int tile = bid;                    // c*64 + k
        const int q    = w;
        const float4* src = reinterpret_cast<const float4*>(
            W1 + ((size_t)tile * 16 + (lane >> 2)) * PP + q * 32 + (lane & 3) * 8);
        const float4 v0 = src[0], v1 = src[1];
        const float vv[8] = {v0.x, v0.y, v0.z, v0.w, v1.x, v1.y, v1.z, v1.w};
        bf16x8 hh;
        #pragma unroll
        for (int e = 0; e < 8; ++e) hh[e] = f2bf(vv[e]);
        const int lp = (lane & 3) * 16 + (lane >> 2);
        *reinterpret_cast<bf16x8*>(W1h + (((size_t)tile * 4 + q) * 64 + lp) * 8) = hh;
    } else if (bid < CC * KK + 1024) {
        // ---- H1 pack: 32x32 fragments, hi/lo planes ----
        const int gw  = (bid - CC * KK) * 4 + w;         // frag id 0..4095
        const int row = (gw >> 3) * 32 + (lane & 31);
        const int col = (gw & 7) * 16 + (lane >> 5) * 8;
        const float4* s = reinterpret_cast<const float4*>(H1 + (size_t)row * PP + col);
        const float4 a = s[0], b = s[1];
        const float vv[8] = {a.x, a.y, a.z, a.w, b.x, b.y, b.z, b.w};
        bf16x8 hh, ll;
        #pragma unroll
        for (int e = 0; e < 8; ++e) {
            const short hv = f2bf(vv[e]);
            hh[e] = hv;
            ll[e] = f2bf(vv[e] - bf2f(hv));
        }
        const size_t o = ((size_t)gw * 64 + lane) * 8;
        *reinterpret_cast<bf16x8*>(H1h32 + o) = hh;
        *reinterpret_cast<bf16x8*>(H1l32 + o) = ll;
    } else if (bid < CC * KK + 1024 + CC) {
        // ---- H2+fc2w pack: per-class 32-row tile, hi/lo ----
        const int cidx = bid - (CC * KK + 1024);
        #pragma unroll
        for (int i = 0; i < 2; ++i) {
            const int q8  = w * 2 + i;
            const int row = lane & 31;
            const int col = q8 * 16 + (lane >> 5) * 8;
            float vv[8];
            if (row < 4) {
                const float4* s = reinterpret_cast<const float4*>(
                    H2 + ((size_t)cidx * 4 + row) * PP + col);
                const float4 a = s[0], b = s[1];
                vv[0]=a.x; vv[1]=a.y; vv[2]=a.z; vv[3]=a.w;
                vv[4]=b.x; vv[5]=b.y; vv[6]=b.z; vv[7]=b.w;
            } else if (row == 4) {
                const float4* s = reinterpret_cast<const float4*>(
                    fc2w + (size_t)cidx * PP + col);
                const float4 a = s[0], b = s[1];
                vv[0]=a.x; vv[1]=a.y; vv[2]=a.z; vv[3]=a.w;
                vv[4]=b.x; vv[5]=b.y; vv[6]=b.z; vv[7]=b.w;
            } else {
                #pragma unroll
                for (int e = 0; e < 8; ++e) vv[e] = 0.f;
            }
            bf16x8 hh, ll;
            #pragma unroll
            for (int e = 0; e < 8; ++e) {
                const short hv = f2bf(vv[e]);
                hh[e] = hv;
                ll[e] = f2bf(vv[e] - bf2f(hv));
            }
            const size_t o = (((size_t)cidx * 8 + q8) * 64 + lane) * 8;
            *reinterpret_cast<bf16x8*>(H2Wh + o) = hh;
            *reinterpret_cast<bf16x8*>(H2Wl + o) = ll;
        }
    } else {
        // ---- x pack (hi plane only): frag = (tile*2+ct)*8 + q8;
        //      row = tile*64 + ct*32 + (l&31), col = q8*16 + (l>>5)*8 ----
        const int frag = (bid - (CC * KK + 1024 + CC)) * 4 + w;   // 0..511
        const int tile = frag >> 4;
        const int ct   = (frag >> 3) & 1;
        const int q8   = frag & 7;
        const int row  = tile * 64 + ct * 32 + (lane & 31);
        const int col  = q8 * 16 + (lane >> 5) * 8;
        const float4* s = reinterpret_cast<const float4*>(x + (size_t)row * PP + col);
        const float4 a = s[0], b = s[1];
        const float vv[8] = {a.x, a.y, a.z, a.w, b.x, b.y, b.z, b.w};
        bf16x8 hh;
        #pragma unroll
        for (int e = 0; e < 8; ++e) hh[e] = f2bf(vv[e]);
        *reinterpret_cast<bf16x8*>(xpk + ((size_t)frag * 64 + lane) * 8) = hh;
    }
}

// ---------------------------------------------------------------------------
// Main predict: one block per (class, 64-token tile).
// Phase A + A2: 32x32x16, 2-pass split ((Hh+Hl)·xh; absmax 1.5 < 2.78
// verified r13-r19). Phase B: 16x16x32, 1-pass, k-outer, ctx preloaded.
// LOAD BATCHING (this round): waves were stalled ~95% of lifetime with
// near-serial global loads (compiler at 64 VGPR issues just-in-time).
// Phase A preloads all 16 A-frags per rt; A2 likewise; Phase B batches
// 8 loads per k-pair. One latency exposure per batch instead of per load.
// launch_bounds (256,4) — ONLY safe setting ((256,5)/(256,6) spilled).
// Spill canary: WRITE_SIZE.
// ---------------------------------------------------------------------------
__global__ __launch_bounds__(256, 4) void predict_kernel(
    const short* __restrict__ xpk,
    const short* __restrict__ H1h32,
    const short* __restrict__ H1l32,
    const short* __restrict__ W1h,
    const short* __restrict__ H2Wh,
    const short* __restrict__ H2Wl,
    const float* __restrict__ W2,
    const float* __restrict__ fc2b,
    float* __restrict__ bout)
{
    __shared__ short xuh[2][8][64][8];        // 16 KB  [ct][q8][l32][e]; l1s alias
    __shared__ unsigned char ctxb[TT][68];    // 4.35 KB
    __shared__ unsigned char bit2b[TT];       // 64 B
    __shared__ float af[TT];                  // 256 B  -> ~20.6 KB total

    const int tid  = threadIdx.x;
    const int lane = tid & 63;
    const int wid  = __builtin_amdgcn_readfirstlane(tid >> 6);
    // XCD swizzle: 2048 blocks = 8 XCD * 256; each XCD owns 8 classes.
    const int bid  = blockIdx.x;
    const int sw   = ((bid & 7) << 8) | (bid >> 3);
    const int c    = sw >> 5;
    const int tile = sw & (NTILES - 1);
    const int tok0 = tile * TT;

    const int t15 = lane & 15;
    const int g   = lane >> 4;
    const int l31 = lane & 31;
    const int l5  = lane >> 5;
    const unsigned laneo = (unsigned)lane * 8u;   // per-lane frag offset (shorts)
    const f32x4  zero4  = {0.f, 0.f, 0.f, 0.f};
    const f32x16 zero16 = {0.f,0.f,0.f,0.f,0.f,0.f,0.f,0.f,
                           0.f,0.f,0.f,0.f,0.f,0.f,0.f,0.f};

    // ---- stage x tile: pure copy from pre-packed bf16 fragment plane -----
    {
        const bf16x8* src = reinterpret_cast<const bf16x8*>(xpk) + (unsigned)tile * 1024u;
        bf16x8* dst = reinterpret_cast<bf16x8*>(&xuh[0][0][0][0]);
        #pragma unroll
        for (int i = 0; i < 4; ++i) {
            const int idx = i * 256 + tid;
            dst[idx] = src[idx];
        }
    }
    __syncthreads();

    // ---- Phase A (32x32x16, 2-pass): all 16 A-frags preloaded per rt -----
    // D: col = lane&31 (token-in-ct), row = (reg&3)+8*(reg>>2)+4*(lane>>5).
    #pragma unroll
    for (int rt = 0; rt < 2; ++rt) {
        const short* hb = H1h32 + (unsigned)((c * 8 + wid * 2 + rt) * 8) * 512u;
        const short* lb = H1l32 + (unsigned)((c * 8 + wid * 2 + rt) * 8) * 512u;
        bf16x8 fh[8], fl[8];
        #pragma unroll
        for (int q8 = 0; q8 < 8; ++q8) {
            const unsigned off = (unsigned)(q8 * 512) + laneo;
            fh[q8] = *reinterpret_cast<const bf16x8*>(hb + off);
            fl[q8] = *reinterpret_cast<const bf16x8*>(lb + off);
        }
        f32x16 aA = zero16, aB = zero16;
        #pragma unroll
        for (int q8 = 0; q8 < 8; ++q8) {
            const bf16x8 bh0 = *reinterpret_cast<const bf16x8*>(&xuh[0][q8][lane][0]);
            const bf16x8 bh1 = *reinterpret_cast<const bf16x8*>(&xuh[1][q8][lane][0]);
            aA = __builtin_amdgcn_mfma_f32_32x32x16_bf16(fh[q8], bh0, aA, 0, 0, 0);
            aA = __builtin_amdgcn_mfma_f32_32x32x16_bf16(fl[q8], bh0, aA, 0, 0, 0);
            aB = __builtin_amdgcn_mfma_f32_32x32x16_bf16(fh[q8], bh1, aB, 0, 0, 0);
            aB = __builtin_amdgcn_mfma_f32_32x32x16_bf16(fl[q8], bh1, aB, 0, 0, 0);
        }
        #pragma unroll
        for (int rg = 0; rg < 4; ++rg) {
            const int k = wid * 16 + rt * 8 + 2 * rg + l5;
            const int cvA = (aA[4*rg+0] > 0.f ? 1 : 0) | (aA[4*rg+1] > 0.f ? 2 : 0) |
                            (aA[4*rg+2] > 0.f ? 4 : 0) | (aA[4*rg+3] > 0.f ? 8 : 0);
            const int cvB = (aB[4*rg+0] > 0.f ? 1 : 0) | (aB[4*rg+1] > 0.f ? 2 : 0) |
                            (aB[4*rg+2] > 0.f ? 4 : 0) | (aB[4*rg+3] > 0.f ? 8 : 0);
            ctxb[l31][k]      = (unsigned char)cvA;
            ctxb[32 + l31][k] = (unsigned char)cvB;
        }
    }

    // ---- A2 (32x32x16, 2-pass): batched loads; waves 0,1 -----------------
    if (wid < 2) {
        const short* hb = H2Wh + (unsigned)(c * 8) * 512u;
        const short* lb = H2Wl + (unsigned)(c * 8) * 512u;
        bf16x8 fh[8], fl[8];
        #pragma unroll
        for (int q8 = 0; q8 < 8; ++q8) {
            const unsigned off = (unsigned)(q8 * 512) + laneo;
            fh[q8] = *reinterpret_cast<const bf16x8*>(hb + off);
            fl[q8] = *reinterpret_cast<const bf16x8*>(lb + off);
        }
        f32x16 a2 = zero16;
        #pragma unroll
        for (int q8 = 0; q8 < 8; ++q8) {
            const bf16x8 bh = *reinterpret_cast<const bf16x8*>(&xuh[wid][q8][lane][0]);
            a2 = __builtin_amdgcn_mfma_f32_32x32x16_bf16(fh[q8], bh, a2, 0, 0, 0);
            a2 = __builtin_amdgcn_mfma_f32_32x32x16_bf16(fl[q8], bh, a2, 0, 0, 0);
        }
        const int tok = wid * 32 + l31;
        if (l5 == 0) {
            bit2b[tok] = (unsigned char)((a2[0] > 0.f ? 1 : 0) | (a2[1] > 0.f ? 2 : 0) |
                                         (a2[2] > 0.f ? 4 : 0) | (a2[3] > 0.f ? 8 : 0));
        } else {
            af[tok] = a2[0];               // row 4 = fc2w . x
        }
    }

    // ---- Phase B (16x16x32, 1-pass): k-pair batched loads ----------------
    // ch preloaded from xuh; after the barrier xuh is dead -> l1s aliases it.
    short* l1s = &xuh[0][0][0][0];         // [tok][k], stride 68 shorts
    {
        bf16x8 ch[4][4];
        #pragma unroll
        for (int j = 0; j < 4; ++j)
            #pragma unroll
            for (int q = 0; q < 4; ++q) {
                const int q8 = 2 * q + (g >> 1);
                const int lw = (g & 1) * 32 + (j & 1) * 16 + t15;
                ch[j][q] = clampfrag(*reinterpret_cast<const bf16x8*>(&xuh[j >> 1][q8][lw][0]));
            }
        // preload this wave's ctx bytes (same-wave RAW: written in Phase A)
        unsigned cxw[4][4];
        #pragma unroll
        for (int j = 0; j < 4; ++j) {
            const int tok = j * 16 + t15;
            #pragma unroll
            for (int i = 0; i < 4; ++i)
                cxw[j][i] = *reinterpret_cast<const unsigned*>(&ctxb[tok][wid * 16 + i * 4]);
        }
        __syncthreads();   // all waves done reading xuh -> safe to overwrite

        const short* wb = W1h + (unsigned)((c * KK + wid * 16) * 4) * 512u;
        #pragma unroll
        for (int kp = 0; kp < 8; ++kp) {
            const int k0 = 2 * kp, k1 = 2 * kp + 1;
            // batch the 8 fragment loads for both k's
            bf16x8 w0[4], w1[4];
            #pragma unroll
            for (int q = 0; q < 4; ++q) {
                const unsigned b0 = (unsigned)(k0 * 2048 + q * 512) + laneo;
                const unsigned b1 = (unsigned)(k1 * 2048 + q * 512) + laneo;
                w0[q] = *reinterpret_cast<const bf16x8*>(wb + b0);
                w1[q] = *reinterpret_cast<const bf16x8*>(wb + b1);
            }
            f32x4 acc0[4] = {zero4, zero4, zero4, zero4};
            f32x4 acc1[4] = {zero4, zero4, zero4, zero4};
            #pragma unroll
            for (int q = 0; q < 4; ++q) {
                #pragma unroll
                for (int j = 0; j < 4; ++j) {
                    acc0[j] = __builtin_amdgcn_mfma_f32_16x16x32_bf16(w0[q], ch[j][q], acc0[j], 0, 0, 0);
                    acc1[j] = __builtin_amdgcn_mfma_f32_16x16x32_bf16(w1[q], ch[j][q], acc1[j], 0, 0, 0);
                }
            }
            #pragma unroll
            for (int j = 0; j < 4; ++j) {
                const int tok = j * 16 + t15;
                {
                    const int cx  = (int)((cxw[j][k0 >> 2] >> ((k0 & 3) * 8)) & 15u);
                    const int sel = cx & 3;
                    const float v = (sel == 0) ? acc0[j][0] : (sel == 1) ? acc0[j][1] :
                                    (sel == 2) ? acc0[j][2] : acc0[j][3];
                    if (g == (cx >> 2))
                        l1s[tok * 68 + wid * 16 + k0] = f2bf(fminf(fmaxf(v, -5.f), 5.f));
                }
                {
                    const int cx  = (int)((cxw[j][k1 >> 2] >> ((k1 & 3) * 8)) & 15u);
                    const int sel = cx & 3;
                    const float v = (sel == 0) ? acc1[j][0] : (sel == 1) ? acc1[j][1] :
                                    (sel == 2) ? acc1[j][2] : acc1[j][3];
                    if (g == (cx >> 2))
                        l1s[tok * 68 + wid * 16 + k1] = f2bf(fminf(fmaxf(v, -5.f), 5.f));
                }
            }
        }
    }
    __syncthreads();

    // ---- epilogue: l2 = W2[ctx2] . l1, alpha, sigmoids, store ------------
    {
        const int tok = tid >> 2;
        const int qt  = tid & 3;
        const int ctx2 = bit2b[tok];
        const float* w2p = W2 + (unsigned)((c * NCTX_ + ctx2) * KK + qt * 16);
        float s = 0.f;
        #pragma unroll
        for (int i4 = 0; i4 < 4; ++i4) {
            const float4 w = *reinterpret_cast<const float4*>(w2p + i4 * 4);
            const int kb = tok * 68 + qt * 16 + i4 * 4;
            s = fmaf(w.x, bf2f(l1s[kb + 0]),
                fmaf(w.y, bf2f(l1s[kb + 1]),
                fmaf(w.z, bf2f(l1s[kb + 2]),
                fmaf(w.w, bf2f(l1s[kb + 3]), s))));
        }
        s += __shfl_xor(s, 1, 64);
        s += __shfl_xor(s, 2, 64);
        if (qt == 0) {
            const float alpha = af[tok] + fc2b[c];
            const float bv = (1.f / (1.f + expf(-s))) * (1.f / (1.f + expf(-alpha)));
            bout[(unsigned)((tok0 + tok) * CC + c)] = bv;
        }
    }
}

// ---------------------------------------------------------------------------
// Fallback predict (small workspace): pure-VALU kernel on original layouts.
// ---------------------------------------------------------------------------
__global__ __launch_bounds__(256, 4) void predict_fb_kernel(
    const float* __restrict__ x,
    const float* __restrict__ H1,
    const float* __restrict__ W1b,
    const float* __restrict__ H2,
    const float* __restrict__ W2,
    const float* __restrict__ fc2w,
    const float* __restrict__ fc2b,
    float* __restrict__ bout)
{
    __shared__ float xs[PP][TT + 1];
    __shared__ float bitss[4][TT];
    __shared__ float apart[4][TT];
    __shared__ float l2part[4][TT];

    const int tid  = threadIdx.x;
    const int lane = tid & 63;
    const int wid  = __builtin_amdgcn_readfirstlane(tid >> 6);
    const int bid  = blockIdx.x;
    const int sw   = ((bid & 7) << 8) | (bid >> 3);
    const int c    = sw >> 5;
    const int tile = sw & (NTILES - 1);
    const int tok0 = tile * TT;

    {
        const float4* xg = reinterpret_cast<const float4*>(x + (size_t)tok0 * PP);
        #pragma unroll
        for (int it = 0; it < (TT * PP / 4) / 256; ++it) {
            const int i = it * 256 + tid;
            const float4 v = xg[i];
            const int t = i >> 5;
            const int p = (i & 31) << 2;
            xs[p + 0][t] = v.x; xs[p + 1][t] = v.y;
            xs[p + 2][t] = v.z; xs[p + 3][t] = v.w;
        }
    }
    __syncthreads();

    int ctxreg[16];
    {
        const float4* H1c4 = reinterpret_cast<const float4*>(H1 + (size_t)c * KK * 4 * PP);
        #pragma unroll
        for (int gg = 0; gg < 8; ++gg) {
            const int k = wid * 16 + gg * 2;
            const float4* h4 = H1c4 + (size_t)k * 4 * 32;
            float acc[8] = {0.f, 0.f, 0.f, 0.f, 0.f, 0.f, 0.f, 0.f};
            #pragma unroll 2
            for (int p4 = 0; p4 < 32; ++p4) {
                const float x0 = xs[4 * p4 + 0][lane];
                const float x1 = xs[4 * p4 + 1][lane];
                const float x2 = xs[4 * p4 + 2][lane];
                const float x3 = xs[4 * p4 + 3][lane];
                #pragma unroll
                for (int r = 0; r < 8; ++r) {
                    const float4 w = h4[r * 32 + p4];
                    acc[r] = fmaf(w.w, x3, fmaf(w.z, x2, fmaf(w.y, x1, fmaf(w.x, x0, acc[r]))));
                }
            }
            ctxreg[gg * 2]     = (acc[0] > 0.f ? 1 : 0) | (acc[1] > 0.f ? 2 : 0) |
                                 (acc[2] > 0.f ? 4 : 0) | (acc[3] > 0.f ? 8 : 0);
            ctxreg[gg * 2 + 1] = (acc[4] > 0.f ? 1 : 0) | (acc[5] > 0.f ? 2 : 0) |
                                 (acc[6] > 0.f ? 4 : 0) | (acc[7] > 0.f ? 8 : 0);
        }
    }
    {
        const float4* h2 = reinterpret_cast<const float4*>(H2 + ((size_t)c * 4 + wid) * PP);
        float d = 0.f;
        #pragma unroll 8
        for (int p4 = 0; p4 < 32; ++p4) {
            const float4 w = h2[p4];
            d = fmaf(w.w, xs[4 * p4 + 3][lane], fmaf(w.z, xs[4 * p4 + 2][lane],
                fmaf(w.y, xs[4 * p4 + 1][lane], fmaf(w.x, xs[4 * p4 + 0][lane], d))));
        }
        bitss[wid][lane] = (d > 0.f) ? 1.f : 0.f;
        const float4* fw = reinterpret_cast<const float4*>(fc2w + (size_t)c * PP) + wid * 8;
        float ap = 0.f;
        #pragma unroll
        for (int p4 = 0; p4 < 8; ++p4) {
            const float4 w = fw[p4];
            const int p = wid * 32 + 4 * p4;
            ap = fmaf(w.w, xs[p + 3][lane], fmaf(w.z, xs[p + 2][lane],
                 fmaf(w.y, xs[p + 1][lane], fmaf(w.x, xs[p + 0][lane], ap))));
        }
        apart[wid][lane] = ap;
    }
    __syncthreads();

    float l1v[16];
    {
        const float4* W1c4 = reinterpret_cast<const float4*>(W1b) +
                             (size_t)(c * KK + wid * 16) * 512;
        #pragma unroll
        for (int gg = 0; gg < 2; ++gg) {
            float s[8] = {0.f, 0.f, 0.f, 0.f, 0.f, 0.f, 0.f, 0.f};
            const float4* wp[8];
            #pragma unroll
            for (int jj = 0; jj < 8; ++jj) {
                const int kk = gg * 8 + jj;
                wp[jj] = W1c4 + (size_t)kk * 512 + (size_t)ctxreg[kk] * 32;
            }
            #pragma unroll 2
            for (int p4 = 0; p4 < 32; ++p4) {
                const float x0 = fminf(fmaxf(xs[4 * p4 + 0][lane], -5.f), 5.f);
                const float x1 = fminf(fmaxf(xs[4 * p4 + 1][lane], -5.f), 5.f);
                const float x2 = fminf(fmaxf(xs[4 * p4 + 2][lane], -5.f), 5.f);
                const float x3 = fminf(fmaxf(xs[4 * p4 + 3][lane], -5.f), 5.f);
                #pragma unroll
                for (int jj = 0; jj < 8; ++jj) {
                    const float4 wv = wp[jj][p4];
                    s[jj] = fmaf(wv.w, x3, fmaf(wv.z, x2, fmaf(wv.y, x1, fmaf(wv.x, x0, s[jj]))));
                }
            }
            #pragma unroll
            for (int jj = 0; jj < 8; ++jj)
                l1v[gg * 8 + jj] = fminf(fmaxf(s[jj], -5.f), 5.f);
        }
    }
    {
        const int ctx2 = (bitss[0][lane] > 0.5f ? 1 : 0) | (bitss[1][lane] > 0.5f ? 2 : 0) |
                         (bitss[2][lane] > 0.5f ? 4 : 0) | (bitss[3][lane] > 0.5f ? 8 : 0);
        const float* w2 = W2 + ((size_t)c * NCTX_ + ctx2) * KK + wid * 16;
        float lp = 0.f;
        #pragma unroll
        for (int jj = 0; jj < 16; ++jj) lp = fmaf(w2[jj], l1v[jj], lp);
        l2part[wid][lane] = lp;
    }
    __syncthreads();
    if (wid == 0) {
        const int t = lane;
        const float l2 = (l2part[0][t] + l2part[1][t]) + (l2part[2][t] + l2part[3][t]);
        const float alpha = apart[0][t] + apart[1][t] + apart[2][t] + apart[3][t] + fc2b[c];
        const float bv = (1.f / (1.f + expf(-l2))) * (1.f / (1.f + expf(-alpha)));
        bout[(size_t)(tok0 + t) * CC + c] = bv;
    }
}

// ---------------------------------------------------------------------------
// Scan: b > 0 and relu-outputs >= 0 => relu is identity for t >= 1; along
// diagonal d the recurrence is a plain cumsum (bit-identical ordering).
// ---------------------------------------------------------------------------
__global__ __launch_bounds__(64) void scan_kernel(const float* __restrict__ hidden,
                                                  float* __restrict__ out)
{
    const int b    = blockIdx.x;
    const int lane = threadIdx.x;
    float* row = out + (size_t)b * SS * CC;
    const float hprev = hidden[b * CC + ((lane + 63) & 63)];

    float nb[64];
    #pragma unroll
    for (int j = 0; j < 64; ++j) nb[j] = row[j * CC + ((lane + j) & 63)];
    float acc = fmaxf(nb[0] + hprev, 0.f);
    row[lane] = acc;
    #pragma unroll
    for (int j = 1; j < 64; ++j) {
        acc += nb[j];
        row[j * CC + ((lane + j) & 63)] = acc;
    }
    for (int c0 = 64; c0 < SS; c0 += 64) {
        #pragma unroll
        for (int j = 0; j < 64; ++j)
            nb[j] = row[(c0 + j) * CC + ((lane + c0 + j) & 63)];
        #pragma unroll
        for (int j = 0; j < 64; ++j) {
            acc += nb[j];
            row[(c0 + j) * CC + ((lane + c0 + j) & 63)] = acc;
        }
    }
    out[(size_t)BB * SS * CC + b * CC + ((lane + 63) & 63)] = acc;
}

extern "C" void kernel_launch(void* const* d_in, const int* in_sizes, int n_in,
                              void* d_out, int out_size, void* d_ws, size_t ws_size,
                              hipStream_t stream) {
    const float* x      = (const float*)d_in[0];
    const float* hidden = (const float*)d_in[1];
    const float* H1     = (const float*)d_in[2];
    const float* W1     = (const float*)d_in[3];
    const float* H2     = (const float*)d_in[4];
    const float* W2     = (const float*)d_in[5];
    const float* fc2w   = (const float*)d_in[6];
    const float* fc2b   = (const float*)d_in[7];
    float* out = (float*)d_out;

    const size_t MB = 1024 * 1024;

    if (ws_size >= 26 * MB) {
        // layout: W1h[16MB] | H1h32[4MB] | H1l32[4MB] |
        //         H2Wh[512KB] | H2Wl[512KB] | xpk[512KB]
        short* W1hp  = (short*)d_ws;
        short* H1hp  = (short*)((char*)d_ws + 16 * MB);
        short* H1lp  = (short*)((char*)d_ws + 20 * MB);
        short* H2Whp = (short*)((char*)d_ws + 24 * MB);
        short* H2Wlp = (short*)((char*)d_ws + 24 * MB + 512 * 1024);
        short* xpkp  = (short*)((char*)d_ws + 25 * MB);
        pack_kernel<<<dim3(CC * KK + 1024 + CC + 128), 256, 0, stream>>>(
            W1, H1, H2, fc2w, x, W1hp, H1hp, H1lp, H2Whp, H2Wlp, xpkp);
        predict_kernel<<<dim3(CC * NTILES), 256, 0, stream>>>(
            xpkp, H1hp, H1lp, W1hp, H2Whp, H2Wlp, W2, fc2b, out);
    } else {
        predict_fb_kernel<<<dim3(CC * NTILES), 256, 0, stream>>>(
            x, H1, W1, H2, W2, fc2w, fc2b, out);
    }
    scan_kernel<<<dim3(BB), 64, 0, stream>>>(hidden, out);
}

// Round 21
// 94.437 us; speedup vs baseline: 1.3773x; 1.3773x over previous
//
#include <hip/hip_runtime.h>
#include <math.h>

#define BB 4
#define SS 512
#define PP 128
#define CC 64
#define KK 64
#define NCTX_ 16
#define TT 64
#define NTILES ((BB*SS)/TT)   // 32

typedef __attribute__((ext_vector_type(8))) short bf16x8;
typedef __attribute__((ext_vector_type(4))) float f32x4;
typedef __attribute__((ext_vector_type(16))) float f32x16;

static __device__ __forceinline__ float bf2f(short h) {
    unsigned u = ((unsigned)(unsigned short)h) << 16;
    return __builtin_bit_cast(float, u);
}
static __device__ __forceinline__ short f2bf(float f) {
    unsigned u = __builtin_bit_cast(unsigned, f);
    unsigned r = (u + 0x7fffu + ((u >> 16) & 1u)) >> 16;
    return (short)(unsigned short)r;
}
// clamp a bf16x8 fragment to [-5,5] in the bf16 bit domain (5.0 = 0x40A0).
static __device__ __forceinline__ bf16x8 clampfrag(bf16x8 h) {
    typedef __attribute__((ext_vector_type(4))) unsigned u32x4;
    u32x4 u = __builtin_bit_cast(u32x4, h);
    #pragma unroll
    for (int i = 0; i < 4; ++i) {
        const unsigned w = u[i];
        const unsigned s = w & 0x80008000u;
        unsigned lo = w & 0x7fffu;
        unsigned hi = (w >> 16) & 0x7fffu;
        lo = lo > 0x40a0u ? 0x40a0u : lo;
        hi = hi > 0x40a0u ? 0x40a0u : hi;
        u[i] = s | lo | (hi << 16);
    }
    return __builtin_bit_cast(bf16x8, u);
}

// ---------------------------------------------------------------------------
// Fused pack kernel (one launch):
//  bid <  4096          : W1 -> 16x16-fragment-major bf16 hi (Phase B operand)
//  bid in [4096, 5120)  : H1 -> 32x32-fragment-major bf16 hi/lo (Phase A)
//  bid in [5120, 5184)  : per-class 32x128 {H2 rows 0-3, fc2w row 4, 0...}
//  bid in [5184, 5312)  : x -> 32x32 B-fragment-major bf16 (hi plane only)
// 32x32x16 A/B fragment layout: elem (row=lane&31, k=(lane>>5)*8+e).
// ---------------------------------------------------------------------------
__global__ __launch_bounds__(256) void pack_kernel(
    const float* __restrict__ W1, const float* __restrict__ H1,
    const float* __restrict__ H2, const float* __restrict__ fc2w,
    const float* __restrict__ x,
    short* __restrict__ W1h, short* __restrict__ H1h32, short* __restrict__ H1l32,
    short* __restrict__ H2Wh, short* __restrict__ H2Wl,
    short* __restrict__ xpk)
{
    const int bid  = blockIdx.x;
    const int w    = threadIdx.x >> 6;
    const int lane = threadIdx.x & 63;

    if (bid < CC * KK) {
        // ---- W1 pack: 16x16 fragments, hi plane only ----
        const int tile = bid;                    // c*64 + k
        const int q    = w;
        const float4* src = reinterpret_cast<const float4*>(
            W1 + ((size_t)tile * 16 + (lane >> 2)) * PP + q * 32 + (lane & 3) * 8);
        const float4 v0 = src[0], v1 = src[1];
        const float vv[8] = {v0.x, v0.y, v0.z, v0.w, v1.x, v1.y, v1.z, v1.w};
        bf16x8 hh;
        #pragma unroll
        for (int e = 0; e < 8; ++e) hh[e] = f2bf(vv[e]);
        const int lp = (lane & 3) * 16 + (lane >> 2);
        *reinterpret_cast<bf16x8*>(W1h + (((size_t)tile * 4 + q) * 64 + lp) * 8) = hh;
    } else if (bid < CC * KK + 1024) {
        // ---- H1 pack: 32x32 fragments, hi/lo planes ----
        const int gw  = (bid - CC * KK) * 4 + w;         // frag id 0..4095
        const int row = (gw >> 3) * 32 + (lane & 31);
        const int col = (gw & 7) * 16 + (lane >> 5) * 8;
        const float4* s = reinterpret_cast<const float4*>(H1 + (size_t)row * PP + col);
        const float4 a = s[0], b = s[1];
        const float vv[8] = {a.x, a.y, a.z, a.w, b.x, b.y, b.z, b.w};
        bf16x8 hh, ll;
        #pragma unroll
        for (int e = 0; e < 8; ++e) {
            const short hv = f2bf(vv[e]);
            hh[e] = hv;
            ll[e] = f2bf(vv[e] - bf2f(hv));
        }
        const size_t o = ((size_t)gw * 64 + lane) * 8;
        *reinterpret_cast<bf16x8*>(H1h32 + o) = hh;
        *reinterpret_cast<bf16x8*>(H1l32 + o) = ll;
    } else if (bid < CC * KK + 1024 + CC) {
        // ---- H2+fc2w pack: per-class 32-row tile, hi/lo ----
        const int cidx = bid - (CC * KK + 1024);
        #pragma unroll
        for (int i = 0; i < 2; ++i) {
            const int q8  = w * 2 + i;
            const int row = lane & 31;
            const int col = q8 * 16 + (lane >> 5) * 8;
            float vv[8];
            if (row < 4) {
                const float4* s = reinterpret_cast<const float4*>(
                    H2 + ((size_t)cidx * 4 + row) * PP + col);
                const float4 a = s[0], b = s[1];
                vv[0]=a.x; vv[1]=a.y; vv[2]=a.z; vv[3]=a.w;
                vv[4]=b.x; vv[5]=b.y; vv[6]=b.z; vv[7]=b.w;
            } else if (row == 4) {
                const float4* s = reinterpret_cast<const float4*>(
                    fc2w + (size_t)cidx * PP + col);
                const float4 a = s[0], b = s[1];
                vv[0]=a.x; vv[1]=a.y; vv[2]=a.z; vv[3]=a.w;
                vv[4]=b.x; vv[5]=b.y; vv[6]=b.z; vv[7]=b.w;
            } else {
                #pragma unroll
                for (int e = 0; e < 8; ++e) vv[e] = 0.f;
            }
            bf16x8 hh, ll;
            #pragma unroll
            for (int e = 0; e < 8; ++e) {
                const short hv = f2bf(vv[e]);
                hh[e] = hv;
                ll[e] = f2bf(vv[e] - bf2f(hv));
            }
            const size_t o = (((size_t)cidx * 8 + q8) * 64 + lane) * 8;
            *reinterpret_cast<bf16x8*>(H2Wh + o) = hh;
            *reinterpret_cast<bf16x8*>(H2Wl + o) = ll;
        }
    } else {
        // ---- x pack (hi plane only): frag = (tile*2+ct)*8 + q8;
        //      row = tile*64 + ct*32 + (l&31), col = q8*16 + (l>>5)*8 ----
        const int frag = (bid - (CC * KK + 1024 + CC)) * 4 + w;   // 0..511
        const int tile = frag >> 4;
        const int ct   = (frag >> 3) & 1;
        const int q8   = frag & 7;
        const int row  = tile * 64 + ct * 32 + (lane & 31);
        const int col  = q8 * 16 + (lane >> 5) * 8;
        const float4* s = reinterpret_cast<const float4*>(x + (size_t)row * PP + col);
        const float4 a = s[0], b = s[1];
        const float vv[8] = {a.x, a.y, a.z, a.w, b.x, b.y, b.z, b.w};
        bf16x8 hh;
        #pragma unroll
        for (int e = 0; e < 8; ++e) hh[e] = f2bf(vv[e]);
        *reinterpret_cast<bf16x8*>(xpk + ((size_t)frag * 64 + lane) * 8) = hh;
    }
}

// ---------------------------------------------------------------------------
// Main predict: one block per (class, 64-token tile).  [r19 configuration —
// best verified: 94.4 us total, predict ~85 us, absmax 1.5]
// Phase A + A2: 32x32x16, 2-pass split ((Hh+Hl)·xh; x-lo dropped).
// Phase A split accumulators (hi/lo chains independent). Phase B: 16x16x32,
// 1-pass, k-outer, ctx bytes preloaded. x staged by pure copy from the
// pre-packed bf16 plane. l1s aliases xuh. LDS 20.6 KB. 3 barriers.
// launch_bounds (256,4) — ONLY safe setting: (256,5) r13, (256,6) r18, and
// source-level load batching r20 all scratch-spilled (WRITE_SIZE 17-115 MB).
// ---------------------------------------------------------------------------
__global__ __launch_bounds__(256, 4) void predict_kernel(
    const short* __restrict__ xpk,
    const short* __restrict__ H1h32,
    const short* __restrict__ H1l32,
    const short* __restrict__ W1h,
    const short* __restrict__ H2Wh,
    const short* __restrict__ H2Wl,
    const float* __restrict__ W2,
    const float* __restrict__ fc2b,
    float* __restrict__ bout)
{
    __shared__ short xuh[2][8][64][8];        // 16 KB  [ct][q8][l32][e]; l1s alias
    __shared__ unsigned char ctxb[TT][68];    // 4.35 KB
    __shared__ unsigned char bit2b[TT];       // 64 B
    __shared__ float af[TT];                  // 256 B  -> ~20.6 KB total

    const int tid  = threadIdx.x;
    const int lane = tid & 63;
    const int wid  = __builtin_amdgcn_readfirstlane(tid >> 6);
    // XCD swizzle: 2048 blocks = 8 XCD * 256; each XCD owns 8 classes.
    const int bid  = blockIdx.x;
    const int sw   = ((bid & 7) << 8) | (bid >> 3);
    const int c    = sw >> 5;
    const int tile = sw & (NTILES - 1);
    const int tok0 = tile * TT;

    const int t15 = lane & 15;
    const int g   = lane >> 4;
    const int l31 = lane & 31;
    const int l5  = lane >> 5;
    const unsigned laneo = (unsigned)lane * 8u;   // per-lane frag offset (shorts)
    const f32x4  zero4  = {0.f, 0.f, 0.f, 0.f};
    const f32x16 zero16 = {0.f,0.f,0.f,0.f,0.f,0.f,0.f,0.f,
                           0.f,0.f,0.f,0.f,0.f,0.f,0.f,0.f};

    // ---- stage x tile: pure copy from pre-packed bf16 fragment plane -----
    {
        const bf16x8* src = reinterpret_cast<const bf16x8*>(xpk) + (unsigned)tile * 1024u;
        bf16x8* dst = reinterpret_cast<bf16x8*>(&xuh[0][0][0][0]);
        #pragma unroll
        for (int i = 0; i < 4; ++i) {
            const int idx = i * 256 + tid;
            dst[idx] = src[idx];
        }
    }
    __syncthreads();

    // ---- Phase A (32x32x16 MFMA, 2-pass, split accumulators) -------------
    // D: col = lane&31 (token-in-ct), row = (reg&3)+8*(reg>>2)+4*(lane>>5).
    #pragma unroll
    for (int rt = 0; rt < 2; ++rt) {
        f32x16 aA0 = zero16, aA1 = zero16, aB0 = zero16, aB1 = zero16;
        const short* hb = H1h32 + (unsigned)((c * 8 + wid * 2 + rt) * 8) * 512u;
        const short* lb = H1l32 + (unsigned)((c * 8 + wid * 2 + rt) * 8) * 512u;
        #pragma unroll
        for (int q8 = 0; q8 < 8; ++q8) {
            const unsigned off = (unsigned)(q8 * 512) + laneo;
            const bf16x8 ah  = *reinterpret_cast<const bf16x8*>(hb + off);
            const bf16x8 al  = *reinterpret_cast<const bf16x8*>(lb + off);
            const bf16x8 bh0 = *reinterpret_cast<const bf16x8*>(&xuh[0][q8][lane][0]);
            const bf16x8 bh1 = *reinterpret_cast<const bf16x8*>(&xuh[1][q8][lane][0]);
            aA0 = __builtin_amdgcn_mfma_f32_32x32x16_bf16(ah, bh0, aA0, 0, 0, 0);
            aA1 = __builtin_amdgcn_mfma_f32_32x32x16_bf16(al, bh0, aA1, 0, 0, 0);
            aB0 = __builtin_amdgcn_mfma_f32_32x32x16_bf16(ah, bh1, aB0, 0, 0, 0);
            aB1 = __builtin_amdgcn_mfma_f32_32x32x16_bf16(al, bh1, aB1, 0, 0, 0);
        }
        const f32x16 aA = aA0 + aA1;
        const f32x16 aB = aB0 + aB1;
        #pragma unroll
        for (int rg = 0; rg < 4; ++rg) {
            const int k = wid * 16 + rt * 8 + 2 * rg + l5;
            const int cvA = (aA[4*rg+0] > 0.f ? 1 : 0) | (aA[4*rg+1] > 0.f ? 2 : 0) |
                            (aA[4*rg+2] > 0.f ? 4 : 0) | (aA[4*rg+3] > 0.f ? 8 : 0);
            const int cvB = (aB[4*rg+0] > 0.f ? 1 : 0) | (aB[4*rg+1] > 0.f ? 2 : 0) |
                            (aB[4*rg+2] > 0.f ? 4 : 0) | (aB[4*rg+3] > 0.f ? 8 : 0);
            ctxb[l31][k]      = (unsigned char)cvA;
            ctxb[32 + l31][k] = (unsigned char)cvB;
        }
    }

    // ---- A2 (32x32x16, 2-pass): rows 0-3 = ctx2 bits, row 4 = alpha ------
    if (wid < 2) {
        f32x16 a20 = zero16, a21 = zero16;
        const short* hb = H2Wh + (unsigned)(c * 8) * 512u;
        const short* lb = H2Wl + (unsigned)(c * 8) * 512u;
        #pragma unroll
        for (int q8 = 0; q8 < 8; ++q8) {
            const unsigned off = (unsigned)(q8 * 512) + laneo;
            const bf16x8 ah = *reinterpret_cast<const bf16x8*>(hb + off);
            const bf16x8 al = *reinterpret_cast<const bf16x8*>(lb + off);
            const bf16x8 bh = *reinterpret_cast<const bf16x8*>(&xuh[wid][q8][lane][0]);
            a20 = __builtin_amdgcn_mfma_f32_32x32x16_bf16(ah, bh, a20, 0, 0, 0);
            a21 = __builtin_amdgcn_mfma_f32_32x32x16_bf16(al, bh, a21, 0, 0, 0);
        }
        const f32x16 a2 = a20 + a21;
        const int tok = wid * 32 + l31;
        if (l5 == 0) {
            bit2b[tok] = (unsigned char)((a2[0] > 0.f ? 1 : 0) | (a2[1] > 0.f ? 2 : 0) |
                                         (a2[2] > 0.f ? 4 : 0) | (a2[3] > 0.f ? 8 : 0));
        } else {
            af[tok] = a2[0];               // row 4 = fc2w . x
        }
    }

    // ---- Phase B (16x16x32, 1-pass): k-outer, ctx bytes preloaded --------
    // ch preloaded from xuh; after the barrier xuh is dead -> l1s aliases it.
    short* l1s = &xuh[0][0][0][0];         // [tok][k], stride 68 shorts
    {
        bf16x8 ch[4][4];
        #pragma unroll
        for (int j = 0; j < 4; ++j)
            #pragma unroll
            for (int q = 0; q < 4; ++q) {
                const int q8 = 2 * q + (g >> 1);
                const int lw = (g & 1) * 32 + (j & 1) * 16 + t15;
                ch[j][q] = clampfrag(*reinterpret_cast<const bf16x8*>(&xuh[j >> 1][q8][lw][0]));
            }
        // preload this wave's ctx bytes (same-wave RAW: written in Phase A)
        unsigned cxw[4][4];
        #pragma unroll
        for (int j = 0; j < 4; ++j) {
            const int tok = j * 16 + t15;
            #pragma unroll
            for (int i = 0; i < 4; ++i)
                cxw[j][i] = *reinterpret_cast<const unsigned*>(&ctxb[tok][wid * 16 + i * 4]);
        }
        __syncthreads();   // all waves done reading xuh -> safe to overwrite

        const short* wb = W1h + (unsigned)((c * KK + wid * 16) * 4) * 512u;
        #pragma unroll
        for (int k16 = 0; k16 < 16; ++k16) {
            const int k = wid * 16 + k16;
            const unsigned ko = (unsigned)(k16 * 2048) + laneo;
            f32x4 acc[4] = {zero4, zero4, zero4, zero4};
            #pragma unroll
            for (int q = 0; q < 4; ++q) {
                const bf16x8 ah = *reinterpret_cast<const bf16x8*>(wb + ko + (unsigned)(q * 512));
                #pragma unroll
                for (int j = 0; j < 4; ++j)
                    acc[j] = __builtin_amdgcn_mfma_f32_16x16x32_bf16(ah, ch[j][q], acc[j], 0, 0, 0);
            }
            #pragma unroll
            for (int j = 0; j < 4; ++j) {
                const int tok = j * 16 + t15;
                const int cx  = (int)((cxw[j][k16 >> 2] >> ((k16 & 3) * 8)) & 15u);
                const int sel = cx & 3;
                const float v = (sel == 0) ? acc[j][0] : (sel == 1) ? acc[j][1] :
                                (sel == 2) ? acc[j][2] : acc[j][3];
                if (g == (cx >> 2))
                    l1s[tok * 68 + k] = f2bf(fminf(fmaxf(v, -5.f), 5.f));
            }
        }
    }
    __syncthreads();

    // ---- epilogue: l2 = W2[ctx2] . l1, alpha, sigmoids, store ------------
    {
        const int tok = tid >> 2;
        const int qt  = tid & 3;
        const int ctx2 = bit2b[tok];
        const float* w2p = W2 + (unsigned)((c * NCTX_ + ctx2) * KK + qt * 16);
        float s = 0.f;
        #pragma unroll
        for (int i4 = 0; i4 < 4; ++i4) {
            const float4 w = *reinterpret_cast<const float4*>(w2p + i4 * 4);
            const int kb = tok * 68 + qt * 16 + i4 * 4;
            s = fmaf(w.x, bf2f(l1s[kb + 0]),
                fmaf(w.y, bf2f(l1s[kb + 1]),
                fmaf(w.z, bf2f(l1s[kb + 2]),
                fmaf(w.w, bf2f(l1s[kb + 3]), s))));
        }
        s += __shfl_xor(s, 1, 64);
        s += __shfl_xor(s, 2, 64);
        if (qt == 0) {
            const float alpha = af[tok] + fc2b[c];
            const float bv = (1.f / (1.f + expf(-s))) * (1.f / (1.f + expf(-alpha)));
            bout[(unsigned)((tok0 + tok) * CC + c)] = bv;
        }
    }
}

// ---------------------------------------------------------------------------
// Fallback predict (small workspace): pure-VALU kernel on original layouts.
// ---------------------------------------------------------------------------
__global__ __launch_bounds__(256, 4) void predict_fb_kernel(
    const float* __restrict__ x,
    const float* __restrict__ H1,
    const float* __restrict__ W1b,
    const float* __restrict__ H2,
    const float* __restrict__ W2,
    const float* __restrict__ fc2w,
    const float* __restrict__ fc2b,
    float* __restrict__ bout)
{
    __shared__ float xs[PP][TT + 1];
    __shared__ float bitss[4][TT];
    __shared__ float apart[4][TT];
    __shared__ float l2part[4][TT];

    const int tid  = threadIdx.x;
    const int lane = tid & 63;
    const int wid  = __builtin_amdgcn_readfirstlane(tid >> 6);
    const int bid  = blockIdx.x;
    const int sw   = ((bid & 7) << 8) | (bid >> 3);
    const int c    = sw >> 5;
    const int tile = sw & (NTILES - 1);
    const int tok0 = tile * TT;

    {
        const float4* xg = reinterpret_cast<const float4*>(x + (size_t)tok0 * PP);
        #pragma unroll
        for (int it = 0; it < (TT * PP / 4) / 256; ++it) {
            const int i = it * 256 + tid;
            const float4 v = xg[i];
            const int t = i >> 5;
            const int p = (i & 31) << 2;
            xs[p + 0][t] = v.x; xs[p + 1][t] = v.y;
            xs[p + 2][t] = v.z; xs[p + 3][t] = v.w;
        }
    }
    __syncthreads();

    int ctxreg[16];
    {
        const float4* H1c4 = reinterpret_cast<const float4*>(H1 + (size_t)c * KK * 4 * PP);
        #pragma unroll
        for (int gg = 0; gg < 8; ++gg) {
            const int k = wid * 16 + gg * 2;
            const float4* h4 = H1c4 + (size_t)k * 4 * 32;
            float acc[8] = {0.f, 0.f, 0.f, 0.f, 0.f, 0.f, 0.f, 0.f};
            #pragma unroll 2
            for (int p4 = 0; p4 < 32; ++p4) {
                const float x0 = xs[4 * p4 + 0][lane];
                const float x1 = xs[4 * p4 + 1][lane];
                const float x2 = xs[4 * p4 + 2][lane];
                const float x3 = xs[4 * p4 + 3][lane];
                #pragma unroll
                for (int r = 0; r < 8; ++r) {
                    const float4 w = h4[r * 32 + p4];
                    acc[r] = fmaf(w.w, x3, fmaf(w.z, x2, fmaf(w.y, x1, fmaf(w.x, x0, acc[r]))));
                }
            }
            ctxreg[gg * 2]     = (acc[0] > 0.f ? 1 : 0) | (acc[1] > 0.f ? 2 : 0) |
                                 (acc[2] > 0.f ? 4 : 0) | (acc[3] > 0.f ? 8 : 0);
            ctxreg[gg * 2 + 1] = (acc[4] > 0.f ? 1 : 0) | (acc[5] > 0.f ? 2 : 0) |
                                 (acc[6] > 0.f ? 4 : 0) | (acc[7] > 0.f ? 8 : 0);
        }
    }
    {
        const float4* h2 = reinterpret_cast<const float4*>(H2 + ((size_t)c * 4 + wid) * PP);
        float d = 0.f;
        #pragma unroll 8
        for (int p4 = 0; p4 < 32; ++p4) {
            const float4 w = h2[p4];
            d = fmaf(w.w, xs[4 * p4 + 3][lane], fmaf(w.z, xs[4 * p4 + 2][lane],
                fmaf(w.y, xs[4 * p4 + 1][lane], fmaf(w.x, xs[4 * p4 + 0][lane], d))));
        }
        bitss[wid][lane] = (d > 0.f) ? 1.f : 0.f;
        const float4* fw = reinterpret_cast<const float4*>(fc2w + (size_t)c * PP) + wid * 8;
        float ap = 0.f;
        #pragma unroll
        for (int p4 = 0; p4 < 8; ++p4) {
            const float4 w = fw[p4];
            const int p = wid * 32 + 4 * p4;
            ap = fmaf(w.w, xs[p + 3][lane], fmaf(w.z, xs[p + 2][lane],
                 fmaf(w.y, xs[p + 1][lane], fmaf(w.x, xs[p + 0][lane], ap))));
        }
        apart[wid][lane] = ap;
    }
    __syncthreads();

    float l1v[16];
    {
        const float4* W1c4 = reinterpret_cast<const float4*>(W1b) +
                             (size_t)(c * KK + wid * 16) * 512;
        #pragma unroll
        for (int gg = 0; gg < 2; ++gg) {
            float s[8] = {0.f, 0.f, 0.f, 0.f, 0.f, 0.f, 0.f, 0.f};
            const float4* wp[8];
            #pragma unroll
            for (int jj = 0; jj < 8; ++jj) {
                const int kk = gg * 8 + jj;
                wp[jj] = W1c4 + (size_t)kk * 512 + (size_t)ctxreg[kk] * 32;
            }
            #pragma unroll 2
            for (int p4 = 0; p4 < 32; ++p4) {
                const float x0 = fminf(fmaxf(xs[4 * p4 + 0][lane], -5.f), 5.f);
                const float x1 = fminf(fmaxf(xs[4 * p4 + 1][lane], -5.f), 5.f);
                const float x2 = fminf(fmaxf(xs[4 * p4 + 2][lane], -5.f), 5.f);
                const float x3 = fminf(fmaxf(xs[4 * p4 + 3][lane], -5.f), 5.f);
                #pragma unroll
                for (int jj = 0; jj < 8; ++jj) {
                    const float4 wv = wp[jj][p4];
                    s[jj] = fmaf(wv.w, x3, fmaf(wv.z, x2, fmaf(wv.y, x1, fmaf(wv.x, x0, s[jj]))));
                }
            }
            #pragma unroll
            for (int jj = 0; jj < 8; ++jj)
                l1v[gg * 8 + jj] = fminf(fmaxf(s[jj], -5.f), 5.f);
        }
    }
    {
        const int ctx2 = (bitss[0][lane] > 0.5f ? 1 : 0) | (bitss[1][lane] > 0.5f ? 2 : 0) |
                         (bitss[2][lane] > 0.5f ? 4 : 0) | (bitss[3][lane] > 0.5f ? 8 : 0);
        const float* w2 = W2 + ((size_t)c * NCTX_ + ctx2) * KK + wid * 16;
        float lp = 0.f;
        #pragma unroll
        for (int jj = 0; jj < 16; ++jj) lp = fmaf(w2[jj], l1v[jj], lp);
        l2part[wid][lane] = lp;
    }
    __syncthreads();
    if (wid == 0) {
        const int t = lane;
        const float l2 = (l2part[0][t] + l2part[1][t]) + (l2part[2][t] + l2part[3][t]);
        const float alpha = apart[0][t] + apart[1][t] + apart[2][t] + apart[3][t] + fc2b[c];
        const float bv = (1.f / (1.f + expf(-l2))) * (1.f / (1.f + expf(-alpha)));
        bout[(size_t)(tok0 + t) * CC + c] = bv;
    }
}

// ---------------------------------------------------------------------------
// Scan: b > 0 and relu-outputs >= 0 => relu is identity for t >= 1; along
// diagonal d the recurrence is a plain cumsum (bit-identical ordering).
// ---------------------------------------------------------------------------
__global__ __launch_bounds__(64) void scan_kernel(const float* __restrict__ hidden,
                                                  float* __restrict__ out)
{
    const int b    = blockIdx.x;
    const int lane = threadIdx.x;
    float* row = out + (size_t)b * SS * CC;
    const float hprev = hidden[b * CC + ((lane + 63) & 63)];

    float nb[64];
    #pragma unroll
    for (int j = 0; j < 64; ++j) nb[j] = row[j * CC + ((lane + j) & 63)];
    float acc = fmaxf(nb[0] + hprev, 0.f);
    row[lane] = acc;
    #pragma unroll
    for (int j = 1; j < 64; ++j) {
        acc += nb[j];
        row[j * CC + ((lane + j) & 63)] = acc;
    }
    for (int c0 = 64; c0 < SS; c0 += 64) {
        #pragma unroll
        for (int j = 0; j < 64; ++j)
            nb[j] = row[(c0 + j) * CC + ((lane + c0 + j) & 63)];
        #pragma unroll
        for (int j = 0; j < 64; ++j) {
            acc += nb[j];
            row[(c0 + j) * CC + ((lane + c0 + j) & 63)] = acc;
        }
    }
    out[(size_t)BB * SS * CC + b * CC + ((lane + 63) & 63)] = acc;
}

extern "C" void kernel_launch(void* const* d_in, const int* in_sizes, int n_in,
                              void* d_out, int out_size, void* d_ws, size_t ws_size,
                              hipStream_t stream) {
    const float* x      = (const float*)d_in[0];
    const float* hidden = (const float*)d_in[1];
    const float* H1     = (const float*)d_in[2];
    const float* W1     = (const float*)d_in[3];
    const float* H2     = (const float*)d_in[4];
    const float* W2     = (const float*)d_in[5];
    const float* fc2w   = (const float*)d_in[6];
    const float* fc2b   = (const float*)d_in[7];
    float* out = (float*)d_out;

    const size_t MB = 1024 * 1024;

    if (ws_size >= 26 * MB) {
        // layout: W1h[16MB] | H1h32[4MB] | H1l32[4MB] |
        //         H2Wh[512KB] | H2Wl[512KB] | xpk[512KB]
        short* W1hp  = (short*)d_ws;
        short* H1hp  = (short*)((char*)d_ws + 16 * MB);
        short* H1lp  = (short*)((char*)d_ws + 20 * MB);
        short* H2Whp = (short*)((char*)d_ws + 24 * MB);
        short* H2Wlp = (short*)((char*)d_ws + 24 * MB + 512 * 1024);
        short* xpkp  = (short*)((char*)d_ws + 25 * MB);
        pack_kernel<<<dim3(CC * KK + 1024 + CC + 128), 256, 0, stream>>>(
            W1, H1, H2, fc2w, x, W1hp, H1hp, H1lp, H2Whp, H2Wlp, xpkp);
        predict_kernel<<<dim3(CC * NTILES), 256, 0, stream>>>(
            xpkp, H1hp, H1lp, W1hp, H2Whp, H2Wlp, W2, fc2b, out);
    } else {
        predict_fb_kernel<<<dim3(CC * NTILES), 256, 0, stream>>>(
            x, H1, W1, H2, W2, fc2w, fc2b, out);
    }
    scan_kernel<<<dim3(BB), 64, 0, stream>>>(hidden, out);
}